// Round 12
// baseline (364.029 us; speedup 1.0000x reference)
//
#include <hip/hip_runtime.h>
#include <hip/hip_bf16.h>

#define N_NODES 50000
#define N_EDGES 1600000
#define BATCH   16384
#define HID     128
#define NBUCK   782          // (N_NODES+63)/64
#define NBLK    256
#define EPB     6250         // NBLK*EPB == N_EDGES

#define CONVB   967          // ceil(CW_TOT/256)
#define PACKB   577          // ceil(PACK_TOT/256)
#define G0A     782          // gemm0 blocks in mix3a (rows 0..25023)
#define G0B     781          // gemm0 blocks in mix3b (rows 25024..49999)

using short8  = __attribute__((ext_vector_type(8))) short;
using floatx4 = __attribute__((ext_vector_type(4))) float;
using floatv4 = __attribute__((ext_vector_type(4))) float;
using float2v = __attribute__((ext_vector_type(2))) float;
using uint2v  = __attribute__((ext_vector_type(2))) unsigned;
using uintx4  = __attribute__((ext_vector_type(4))) unsigned;
typedef unsigned short ushort_t;

__device__ __forceinline__ float bflo(unsigned u){ return __uint_as_float(u << 16); }
__device__ __forceinline__ float bfhi(unsigned u){ return __uint_as_float(u & 0xffff0000u); }
__device__ __forceinline__ float bf1(ushort_t u){ return __uint_as_float(((unsigned)u) << 16); }
__device__ __forceinline__ ushort_t f2bf(float f){
    unsigned u = __float_as_uint(f);
    return (ushort_t)((u + 0x7fffu + ((u >> 16) & 1u)) >> 16);   // RNE
}
__device__ __forceinline__ int geti(const void* p, long long i, int is64){
    return is64 ? (int)((const long long*)p)[i] : ((const int*)p)[i];
}
__device__ __forceinline__ float2v up2(unsigned u){
    float2v r; r.x = bflo(u); r.y = bfhi(u); return r;
}

// canonical arena offsets (ushort units)
#define OFF_WL0 0
#define OFF_WR0 32768
#define OFF_WL1 65536
#define OFF_WR1 81920
#define OFF_B0  98304
#define OFF_B1  98432
#define OFF_EPW 98560
#define OFF_EPB 98944
#define OFF_P1W 99008
#define OFF_P1B 139968
#define OFF_BNG 140096
#define OFF_BNB 140224
#define OFF_BNM 140352
#define OFF_BNV 140480
#define OFF_P2W 140608
#define OFF_P2B 148800
#define OFF_P3W 148864
#define OFF_EF  148928
#define OFF_P3B 247232
#define CW_TOT  247233
#define PACK_TOT 147584

// ---------------- dtype detection (parallel) ----------------
__global__ void k_detect(const unsigned* __restrict__ xbits,
                         const unsigned* __restrict__ eibits, int* flags){
    __shared__ int f[2];
    int t = threadIdx.x;
    if (t < 2) f[t] = 0;
    __syncthreads();
    unsigned u = xbits[t];
    unsigned e0 = (u >> 7)  & 0xFF;
    unsigned e1 = (u >> 23) & 0xFF;
    if (e0 >= 140 || e1 >= 140) atomicOr(&f[0], 1);
    if (eibits[2*t + 1] != 0)   atomicOr(&f[1], 1);
    __syncthreads();
    if (t == 0){ flags[0] = f[0]; flags[1] = f[1] ? 0 : 1; }
}

#define NT 19
struct ConvDesc { const void* src[NT]; int cum[NT + 1]; };

// ---------------- mix1: weight-arena convert || edge histogram ----------------
__global__ __launch_bounds__(256)
void k_mix1(ConvDesc d, ushort_t* __restrict__ cw,
            const void* __restrict__ ei, int* __restrict__ hist,
            const int* __restrict__ flags){
    __shared__ int lh[NBUCK];
    if (blockIdx.x < CONVB){
        int i = blockIdx.x*256 + threadIdx.x;
        if (i >= d.cum[NT]) return;
        int seg = 0;
        while (i >= d.cum[seg + 1]) seg++;
        int off = i - d.cum[seg];
        ushort_t v;
        if (flags[0]) v = f2bf(((const float*)d.src[seg])[off]);
        else          v = ((const ushort_t*)d.src[seg])[off];
        cw[i] = v;
    } else {
        int b = blockIdx.x - CONVB;
        for (int i = threadIdx.x; i < NBUCK; i += 256) lh[i] = 0;
        __syncthreads();
        int i64 = flags[1];
        int e0 = b * EPB;
        for (int e = e0 + threadIdx.x; e < e0 + EPB; e += 256){
            int dd = geti(ei, (long long)N_EDGES + e, i64);
            atomicAdd(&lh[dd >> 6], 1);
        }
        __syncthreads();
        for (int i = threadIdx.x; i < NBUCK; i += 256)
            hist[i * NBLK + b] = lh[i];
    }
}

// ---------------- mix2: MFMA weight pre-pack + BN fold || scancol ----------------
__global__ __launch_bounds__(256)
void k_mix2(const ushort_t* __restrict__ cw,
            ushort_t* __restrict__ bp0, ushort_t* __restrict__ bp1,
            ushort_t* __restrict__ bpp1, ushort_t* __restrict__ bpp2,
            float* __restrict__ bnf,
            int* __restrict__ hist, int* __restrict__ btot){
    __shared__ int sh[256];
    if (blockIdx.x < PACKB){
        int i = blockIdx.x*256 + threadIdx.x;
        if (i < 65536){
            int j = i & 7, lane = (i >> 3) & 63, c = (i >> 9) & 15, kk = i >> 13;
            int k = kk*32 + (lane >> 4)*8 + j;
            int n = c*16 + (lane & 15);
            bp0[i] = (n < 128) ? cw[OFF_WL0 + k*128 + n] : cw[OFF_WR0 + k*128 + (n-128)];
        } else if (i < 98304){
            int i2 = i - 65536;
            int j = i2 & 7, lane = (i2 >> 3) & 63, c = (i2 >> 9) & 15, kk = i2 >> 13;
            int k = kk*32 + (lane >> 4)*8 + j;
            int n = c*16 + (lane & 15);
            bp1[i2] = (n < 128) ? cw[OFF_WL1 + k*128 + n] : cw[OFF_WR1 + k*128 + (n-128)];
        } else if (i < 139264){
            int i2 = i - 98304;                     // p1_w [320][128] -> frag order
            int j = i2 & 7, lane = (i2 >> 3) & 63, ct = (i2 >> 9) & 7, kk = i2 >> 12;
            int k = kk*32 + (lane >> 4)*8 + j;
            int n = ct*16 + (lane & 15);
            bpp1[i2] = cw[OFF_P1W + k*128 + n];
        } else if (i < 147456){
            int i2 = i - 139264;                    // p2_w [128][64] -> frag order
            int j = i2 & 7, lane = (i2 >> 3) & 63, ct = (i2 >> 9) & 3, kk = i2 >> 11;
            int k = kk*32 + (lane >> 4)*8 + j;
            int n = ct*16 + (lane & 15);
            bpp2[i2] = cw[OFF_P2W + k*64 + n];
        } else if (i < PACK_TOT){
            int n = i - 147456;                     // BN fold: scale/shift fp32
            float g = bf1(cw[OFF_BNG + n]), b = bf1(cw[OFF_BNB + n]);
            float m = bf1(cw[OFF_BNM + n]), v = bf1(cw[OFF_BNV + n]);
            float sc = g / sqrtf(v + 1e-5f);
            bnf[n] = sc; bnf[128 + n] = b - m*sc;
        }
    } else {
        int b = blockIdx.x - PACKB, t = threadIdx.x;
        int v = hist[b*NBLK + t];
        sh[t] = v; __syncthreads();
        for (int o = 1; o < 256; o <<= 1){
            int x = (t >= o) ? sh[t-o] : 0;
            __syncthreads();
            sh[t] += x;
            __syncthreads();
        }
        hist[b*NBLK + t] = sh[t] - v;
        if (t == 255) btot[b] = sh[255];
    }
}

__global__ __launch_bounds__(1024)
void kb_scanbase(const int* __restrict__ btot, int* __restrict__ bbase,
                 int* __restrict__ off){
    __shared__ int sh[1024];
    int t = threadIdx.x;
    int v = (t < NBUCK) ? btot[t] : 0;
    sh[t] = v; __syncthreads();
    for (int o = 1; o < 1024; o <<= 1){
        int x = (t >= o) ? sh[t-o] : 0;
        __syncthreads();
        sh[t] += x;
        __syncthreads();
    }
    if (t < NBUCK) bbase[t] = sh[t] - v;
    if (t == 0){ bbase[NBUCK] = N_EDGES; off[N_NODES] = N_EDGES; }
}

// ---------------- unified layer-0 GEMM body (bf16 or fp32 A at runtime) ----------------
// 32-row block, wave = 16 rows x 128 cols. Col-half 0 -> ytab, col-half 1 -> rtab
// (split tables halve the k_agg gather working set: 25.6 -> 12.8 MB).
__device__ __forceinline__ void gemm0_body(const void* __restrict__ xin,
                                           const ushort_t* __restrict__ Bp,
                                           ushort_t* __restrict__ ytab,
                                           ushort_t* __restrict__ rtab,
                                           int M, int f32, int blk){
    const int t = threadIdx.x;
    const int lane = t & 63;
    const int w = t >> 6;
    const int rg = w >> 1, cg = w & 1;
    const int l16 = lane & 15, q = lane >> 4;
    const int m_base = blk * 32 + rg * 16;
    int m = m_base + l16;
    bool ok = (m < M);
    const short8* bbase = (const short8*)Bp + lane;

    floatx4 acc[8] = {};
    if (f32){
        const float* arow = (const float*)xin + (size_t)(ok ? m : 0)*256 + q*8;
        for (int kk = 0; kk < 8; ++kk){
            union { unsigned u[4]; short8 s; } cv;
            cv.u[0]=0; cv.u[1]=0; cv.u[2]=0; cv.u[3]=0;
            if (ok){
                floatv4 f0 = *(const floatv4*)(arow + kk*32);
                floatv4 f1 = *(const floatv4*)(arow + kk*32 + 4);
                cv.u[0] = __builtin_amdgcn_perm(__float_as_uint(f0.y), __float_as_uint(f0.x), 0x07060302);
                cv.u[1] = __builtin_amdgcn_perm(__float_as_uint(f0.w), __float_as_uint(f0.z), 0x07060302);
                cv.u[2] = __builtin_amdgcn_perm(__float_as_uint(f1.y), __float_as_uint(f1.x), 0x07060302);
                cv.u[3] = __builtin_amdgcn_perm(__float_as_uint(f1.w), __float_as_uint(f1.z), 0x07060302);
            }
            #pragma unroll
            for (int ci = 0; ci < 8; ++ci){
                short8 b = bbase[(kk*16 + cg*8 + ci)*64];
                acc[ci] = __builtin_amdgcn_mfma_f32_16x16x32_bf16(cv.s, b, acc[ci], 0, 0, 0);
            }
        }
    } else {
        const ushort_t* arow = (const ushort_t*)xin + (size_t)(ok ? m : 0)*256 + q*8;
        for (int kk = 0; kk < 8; ++kk){
            short8 a = {0,0,0,0,0,0,0,0};
            if (ok) a = *(const short8*)(arow + kk*32);
            #pragma unroll
            for (int ci = 0; ci < 8; ++ci){
                short8 b = bbase[(kk*16 + cg*8 + ci)*64];
                acc[ci] = __builtin_amdgcn_mfma_f32_16x16x32_bf16(a, b, acc[ci], 0, 0, 0);
            }
        }
    }
    ushort_t* dst = cg ? rtab : ytab;
    int row_b = m_base + q*4;
    #pragma unroll
    for (int r = 0; r < 4; ++r){
        int row = row_b + r;
        if (row < M){
            #pragma unroll
            for (int ci = 0; ci < 8; ++ci)
                dst[(size_t)row*128 + ci*16 + l16] = f2bf(acc[ci][r]);
        }
    }
}

// ---------------- mix3a: gemm0 rows 0..25023 || edge scatter (interleaved roles) ----------------
__global__ __launch_bounds__(256)
void k_mix3a(const void* __restrict__ x, const ushort_t* __restrict__ bp0,
             ushort_t* __restrict__ ytab, ushort_t* __restrict__ rtab,
             const void* __restrict__ ei, const int* __restrict__ hist,
             const int* __restrict__ bbase, unsigned* __restrict__ ebuf,
             const int* __restrict__ flags){
    __shared__ int lcur[NBUCK];
    // scatter role: every 4th block among the first 1024 (256 total), so scatter
    // co-resides with gemm on each CU instead of queueing behind all gemm blocks.
    bool scat = (blockIdx.x < 1024) && ((blockIdx.x & 3) == 3);
    if (!scat){
        int gi = (blockIdx.x < 1024) ? (int)(blockIdx.x - (blockIdx.x >> 2))
                                     : (int)(blockIdx.x - NBLK);
        gemm0_body(x, bp0, ytab, rtab, N_NODES, flags[0], gi);
    } else {
        int b = blockIdx.x >> 2;
        for (int i = threadIdx.x; i < NBUCK; i += 256)
            lcur[i] = bbase[i] + hist[i*NBLK + b];
        __syncthreads();
        int i64 = flags[1];
        int e0 = b * EPB;
        for (int e = e0 + threadIdx.x; e < e0 + EPB; e += 256){
            int s = geti(ei, e, i64);
            int d = geti(ei, (long long)N_EDGES + e, i64);
            int p = atomicAdd(&lcur[d >> 6], 1);
            ebuf[p] = (unsigned)s | ((unsigned)(d & 63) << 16);
        }
    }
}

// ---------------- mix3b: gemm0 rows 25024..49999 || per-bucket CSR (interleaved) ----------------
__global__ __launch_bounds__(256)
void k_mix3b(const void* __restrict__ x, const ushort_t* __restrict__ bp0,
             ushort_t* __restrict__ ytab, ushort_t* __restrict__ rtab,
             const unsigned* __restrict__ ebuf, const int* __restrict__ bbase,
             ushort_t* __restrict__ csr, int* __restrict__ off,
             const int* __restrict__ flags){
    __shared__ int ldeg[64];
    // grid = 1563: even blocks (782) -> csr, odd blocks (781) -> gemm
    if (blockIdx.x & 1){
        gemm0_body(x, bp0, ytab, rtab, N_NODES, flags[0], G0A + (int)(blockIdx.x >> 1));
    } else {
        int b = blockIdx.x >> 1, t = threadIdx.x;
        int ebase = bbase[b], eend = bbase[b+1];
        if (t < 64) ldeg[t] = 0;
        __syncthreads();
        for (int i = ebase + t; i < eend; i += 256)
            atomicAdd(&ldeg[(ebuf[i] >> 16) & 63], 1);
        __syncthreads();
        if (t < 64){
            int v = ldeg[t];
            int sum = v;
            #pragma unroll
            for (int o = 1; o < 64; o <<= 1){
                int x2 = __shfl_up(sum, o, 64);
                if (t >= o) sum += x2;
            }
            int excl = sum - v;
            int node = b*64 + t;
            if (node < N_NODES) off[node] = ebase + excl;
            ldeg[t] = excl;
        }
        __syncthreads();
        for (int i = ebase + t; i < eend; i += 256){
            unsigned u = ebuf[i];
            int p = atomicAdd(&ldeg[(u >> 16) & 63], 1);
            csr[ebase + p] = (ushort_t)(u & 0xffffu);
        }
    }
}

// ---------------- layer-1 GEMM (bf16 A): 32-row block, split outputs ----------------
__global__ __launch_bounds__(256)
void k_gemm1(const ushort_t* __restrict__ A, const ushort_t* __restrict__ Bp,
             ushort_t* __restrict__ ytab, ushort_t* __restrict__ rtab, int M)
{
    const int KSTEPS = 4;
    const int lane = threadIdx.x & 63;
    const int w    = threadIdx.x >> 6;
    const int rg   = w >> 1;
    const int cg   = w & 1;
    const int l16  = lane & 15;
    const int q    = lane >> 4;
    const int S    = KSTEPS * 32;
    const int m_base = blockIdx.x * 32 + rg * 16;

    int m = m_base + l16;
    bool ok = (m < M);
    const ushort_t* arow = A + (size_t)(ok ? m : 0) * S + q*8;
    const short8* bbase = (const short8*)Bp + lane;

    floatx4 acc[8] = {};
    for (int kk = 0; kk < KSTEPS; ++kk){
        short8 a = {0,0,0,0,0,0,0,0};
        if (ok) a = *(const short8*)(arow + kk*32);
        #pragma unroll
        for (int ci = 0; ci < 8; ++ci){
            short8 b = bbase[(kk*16 + cg*8 + ci)*64];
            acc[ci] = __builtin_amdgcn_mfma_f32_16x16x32_bf16(a, b, acc[ci], 0, 0, 0);
        }
    }

    ushort_t* dst = cg ? rtab : ytab;
    int row_b = m_base + q*4;
    #pragma unroll
    for (int r = 0; r < 4; ++r){
        int row = row_b + r;
        if (row < M){
            #pragma unroll
            for (int ci = 0; ci < 8; ++ci)
                dst[(size_t)row*128 + ci*16 + l16] = f2bf(acc[ci][r]);
        }
    }
}

// ---------------- Aggregation: out[v] = mean(ytab[csr]) + bias + rtab[v] ----------------
// Wave per node; 16-lane groups g cover edges p+g; lane covers 16B of the 256B row.
// FOUR independent streams (16 edges, 4KB in flight). Gather table = 12.8 MB.
__global__ __launch_bounds__(256)
void k_agg(const int* __restrict__ off, const ushort_t* __restrict__ csr,
           const ushort_t* __restrict__ ytab, const ushort_t* __restrict__ rtab,
           const ushort_t* __restrict__ bias,
           ushort_t* __restrict__ out, int do_relu)
{
    int v = blockIdx.x*4 + (threadIdx.x >> 6);
    if (v >= N_NODES) return;
    const int l = threadIdx.x & 63;
    const int g = l >> 4;          // edge subgroup
    const int c = l & 15;          // 16B chunk: bf16 cols c*8..c*8+8
    int e0 = off[v], e1 = off[v+1];
    const ushort_t* yb = ytab + c*8;

    float2v A0[4] = {}, A1[4] = {}, A2[4] = {}, A3[4] = {};
    int p = e0;
    for (; p + 16 <= e1; p += 16){
        int u0 = csr[p + g];
        int u1 = csr[p + 4 + g];
        int u2 = csr[p + 8 + g];
        int u3 = csr[p + 12 + g];
        uintx4 d0 = *(const uintx4*)(yb + (size_t)u0*128);
        uintx4 d1 = *(const uintx4*)(yb + (size_t)u1*128);
        uintx4 d2 = *(const uintx4*)(yb + (size_t)u2*128);
        uintx4 d3 = *(const uintx4*)(yb + (size_t)u3*128);
        A0[0] += up2(d0.x); A0[1] += up2(d0.y); A0[2] += up2(d0.z); A0[3] += up2(d0.w);
        A1[0] += up2(d1.x); A1[1] += up2(d1.y); A1[2] += up2(d1.z); A1[3] += up2(d1.w);
        A2[0] += up2(d2.x); A2[1] += up2(d2.y); A2[2] += up2(d2.z); A2[3] += up2(d2.w);
        A3[0] += up2(d3.x); A3[1] += up2(d3.y); A3[2] += up2(d3.z); A3[3] += up2(d3.w);
    }
    for (; p + 4 <= e1; p += 4){
        int u0 = csr[p + g];
        uintx4 d0 = *(const uintx4*)(yb + (size_t)u0*128);
        A0[0] += up2(d0.x); A0[1] += up2(d0.y); A0[2] += up2(d0.z); A0[3] += up2(d0.w);
    }
    if (p + g < e1){
        int u1 = csr[p + g];
        uintx4 d1 = *(const uintx4*)(yb + (size_t)u1*128);
        A1[0] += up2(d1.x); A1[1] += up2(d1.y); A1[2] += up2(d1.z); A1[3] += up2(d1.w);
    }
    #pragma unroll
    for (int j = 0; j < 4; ++j) A0[j] += A1[j] + A2[j] + A3[j];

    float a0=A0[0].x, a1=A0[0].y, a2=A0[1].x, a3=A0[1].y;
    float a4=A0[2].x, a5=A0[2].y, a6=A0[3].x, a7=A0[3].y;
    #pragma unroll
    for (int m = 16; m <= 32; m <<= 1){
        a0 += __shfl_xor(a0, m, 64); a1 += __shfl_xor(a1, m, 64);
        a2 += __shfl_xor(a2, m, 64); a3 += __shfl_xor(a3, m, 64);
        a4 += __shfl_xor(a4, m, 64); a5 += __shfl_xor(a5, m, 64);
        a6 += __shfl_xor(a6, m, 64); a7 += __shfl_xor(a7, m, 64);
    }
    if (g == 0){
        float inv = 1.f / (float)max(e1 - e0, 1);
        uintx4 rr = *(const uintx4*)(rtab + (size_t)v*128 + c*8);
        uintx4 bb = *(const uintx4*)(bias + c*8);
        float v0 = a0*inv + bflo(rr.x) + bflo(bb.x);
        float v1 = a1*inv + bfhi(rr.x) + bfhi(bb.x);
        float v2 = a2*inv + bflo(rr.y) + bflo(bb.y);
        float v3 = a3*inv + bfhi(rr.y) + bfhi(bb.y);
        float v4 = a4*inv + bflo(rr.z) + bflo(bb.z);
        float v5 = a5*inv + bfhi(rr.z) + bfhi(bb.z);
        float v6 = a6*inv + bflo(rr.w) + bflo(bb.w);
        float v7 = a7*inv + bfhi(rr.w) + bfhi(bb.w);
        if (do_relu){
            v0=fmaxf(v0,0.f); v1=fmaxf(v1,0.f); v2=fmaxf(v2,0.f); v3=fmaxf(v3,0.f);
            v4=fmaxf(v4,0.f); v5=fmaxf(v5,0.f); v6=fmaxf(v6,0.f); v7=fmaxf(v7,0.f);
        }
        uintx4 o;
        o.x = (unsigned)f2bf(v0) | ((unsigned)f2bf(v1) << 16);
        o.y = (unsigned)f2bf(v2) | ((unsigned)f2bf(v3) << 16);
        o.z = (unsigned)f2bf(v4) | ((unsigned)f2bf(v5) << 16);
        o.w = (unsigned)f2bf(v6) | ((unsigned)f2bf(v7) << 16);
        *(uintx4*)(out + (size_t)v*128 + c*8) = o;
    }
}

// ---------------- MFMA predictor: one block = 64 batch rows ----------------
__global__ __launch_bounds__(256)
void k_pred2(const ushort_t* __restrict__ h2,
             const void* __restrict__ srcn, const void* __restrict__ tgtn,
             const ushort_t* __restrict__ cw, const ushort_t* __restrict__ bpp1,
             const ushort_t* __restrict__ bpp2, const float* __restrict__ bnf,
             void* __restrict__ outp, const int* __restrict__ flags)
{
    __shared__ ushort_t comb[64][328];
    __shared__ ushort_t zbuf[64][136];
    __shared__ ushort_t z2buf[64][68];
    __shared__ float    partial[4][64];
    __shared__ int      sid[64], tid_[64];

    const int t    = threadIdx.x;
    const int lane = t & 63;
    const int w    = t >> 6;
    const int l16  = lane & 15;
    const int q    = lane >> 4;
    const int row0 = blockIdx.x * 64;
    const int i64  = flags[1];

    if (t < 64){ sid[t] = geti(srcn, row0 + t, i64); tid_[t] = geti(tgtn, row0 + t, i64); }
    __syncthreads();

    const unsigned* h2u = (const unsigned*)h2;
    #pragma unroll 4
    for (int r = w*16; r < w*16 + 16; ++r){
        unsigned us = h2u[(size_t)sid[r]*64 + lane];
        unsigned ut = h2u[(size_t)tid_[r]*64 + lane];
        *(unsigned*)&comb[r][2*lane]       = us;
        *(unsigned*)&comb[r][128 + 2*lane] = ut;
    }
    {
        int r = t >> 2, c0 = (t & 3) * 16;
        float efv[6];
        #pragma unroll
        for (int k = 0; k < 6; ++k) efv[k] = bf1(cw[OFF_EF + (row0 + r)*6 + k]);
        #pragma unroll
        for (int c = 0; c < 16; ++c){
            int n = c0 + c;
            float a = bf1(cw[OFF_EPB + n]);
            #pragma unroll
            for (int k = 0; k < 6; ++k) a += efv[k] * bf1(cw[OFF_EPW + k*64 + n]);
            comb[r][256 + n] = f2bf(fmaxf(a, 0.f));
        }
    }
    __syncthreads();

    floatx4 acc[4][2] = {};
    for (int kk = 0; kk < 10; ++kk){
        short8 a[4];
        #pragma unroll
        for (int rt = 0; rt < 4; ++rt)
            a[rt] = *(const short8*)&comb[rt*16 + l16][kk*32 + q*8];
        #pragma unroll
        for (int ci = 0; ci < 2; ++ci){
            short8 b = *(const short8*)&bpp1[(((kk*8) + (w*2 + ci))*64 + lane)*8];
            #pragma unroll
            for (int rt = 0; rt < 4; ++rt)
                acc[rt][ci] = __builtin_amdgcn_mfma_f32_16x16x32_bf16(a[rt], b, acc[rt][ci], 0, 0, 0);
        }
    }
    #pragma unroll
    for (int ci = 0; ci < 2; ++ci){
        int n = w*32 + ci*16 + l16;
        float b1v = bf1(cw[OFF_P1B + n]);
        float sc = bnf[n], sh = bnf[128 + n];
        #pragma unroll
        for (int rt = 0; rt < 4; ++rt)
            #pragma unroll
            for (int r = 0; r < 4; ++r){
                float v = fmaxf(acc[rt][ci][r] + b1v, 0.f) * sc + sh;
                zbuf[rt*16 + q*4 + r][n] = f2bf(v);
            }
    }
    __syncthreads();

    floatx4 acc2[4] = {};
    for (int kk = 0; kk < 4; ++kk){
        short8 b = *(const short8*)&bpp2[(((kk*4) + w)*64 + lane)*8];
        #pragma unroll
        for (int rt = 0; rt < 4; ++rt){
            short8 a = *(const short8*)&zbuf[rt*16 + l16][kk*32 + q*8];
            acc2[rt] = __builtin_amdgcn_mfma_f32_16x16x32_bf16(a, b, acc2[rt], 0, 0, 0);
        }
    }
    {
        int n = w*16 + l16;
        float b2v = bf1(cw[OFF_P2B + n]);
        #pragma unroll
        for (int rt = 0; rt < 4; ++rt)
            #pragma unroll
            for (int r = 0; r < 4; ++r)
                z2buf[rt*16 + q*4 + r][n] = f2bf(fmaxf(acc2[rt][r] + b2v, 0.f));
    }
    __syncthreads();

    {
        int r = t & 63, seg = t >> 6;
        float s = 0.f;
        #pragma unroll
        for (int c = 0; c < 16; ++c){
            int n = seg*16 + c;
            s += bf1(z2buf[r][n]) * bf1(cw[OFF_P3W + n]);
        }
        partial[seg][r] = s;
    }
    __syncthreads();
    if (t < 64){
        float zf = partial[0][t] + partial[1][t] + partial[2][t] + partial[3][t] + bf1(cw[OFF_P3B]);
        float sg = 1.f / (1.f + __expf(-zf));
        if (flags[0]) ((float*)outp)[row0 + t] = sg;
        else          ((ushort_t*)outp)[row0 + t] = f2bf(sg);
    }
}

extern "C" void kernel_launch(void* const* d_in, const int* in_sizes, int n_in,
                              void* d_out, int out_size, void* d_ws, size_t ws_size,
                              hipStream_t stream)
{
    const void* x    = d_in[0];
    const void* ei   = d_in[1];
    const void* srcn = d_in[2];
    const void* tgtn = d_in[3];

    char* p = (char*)d_ws;
    auto carve = [&](size_t bytes)->char*{ char* r = p; p += (bytes + 511) & ~size_t(511); return r; };
    int* flags = (int*)carve(64);
    int* off   = (int*)carve((N_NODES+1)*4);
    int* btot  = (int*)carve(NBUCK*4);
    int* bbase = (int*)carve((NBUCK+1)*4);
    ushort_t* csr  = (ushort_t*)carve((size_t)N_EDGES*2);
    ushort_t* ytab = (ushort_t*)carve((size_t)N_NODES*128*2);
    ushort_t* rtab = (ushort_t*)carve((size_t)N_NODES*128*2);
    ushort_t* h    = (ushort_t*)carve((size_t)N_NODES*128*2);
    ushort_t* cw   = (ushort_t*)carve((size_t)CW_TOT*2);
    ushort_t* bp0  = (ushort_t*)carve((size_t)65536*2);
    ushort_t* bp1  = (ushort_t*)carve((size_t)32768*2);
    ushort_t* bpp1 = (ushort_t*)carve((size_t)40960*2);
    ushort_t* bpp2 = (ushort_t*)carve((size_t)8192*2);
    float*    bnf  = (float*)carve(256*4);

    // hist (0.8 MB) + ebuf (6.4 MB) alias into h (12.8 MB): h is first written
    // by k_agg(relu=1), which runs AFTER kb_csr (inside mix3b) consumed ebuf.
    int*      hist = (int*)h;
    unsigned* ebuf = (unsigned*)((char*)h + 1u*1024*1024);

    k_detect<<<1, 256, 0, stream>>>((const unsigned*)x, (const unsigned*)ei, flags);

    ConvDesc cd;
    const int srcidx[NT] = {5,7,8,10,6,9,11,12,13,14,15,16,17,18,19,20,21,4,22};
    const int lens[NT]   = {32768,32768,16384,16384,128,128,384,64,40960,128,128,128,128,128,8192,64,64,98304,1};
    int run = 0;
    for (int i = 0; i < NT; ++i){ cd.src[i] = d_in[srcidx[i]]; cd.cum[i] = run; run += lens[i]; }
    cd.cum[NT] = run;

    k_mix1<<<CONVB + NBLK, 256, 0, stream>>>(cd, cw, ei, hist, flags);
    k_mix2<<<PACKB + NBUCK, 256, 0, stream>>>(cw, bp0, bp1, bpp1, bpp2, bnf, hist, btot);
    kb_scanbase<<<1, 1024, 0, stream>>>(btot, bbase, off);
    k_mix3a<<<G0A + NBLK, 256, 0, stream>>>(x, bp0, ytab, rtab, ei, hist, bbase, ebuf, flags);
    k_mix3b<<<G0B + NBUCK, 256, 0, stream>>>(x, bp0, ytab, rtab, ebuf, bbase, csr, off, flags);

    k_agg<<<(N_NODES+3)/4, 256, 0, stream>>>(off, csr, ytab, rtab, cw+OFF_B0, h, 1);
    k_gemm1<<<(N_NODES + 31)/32, 256, 0, stream>>>(h, bp1, ytab, rtab, N_NODES);
    k_agg<<<(N_NODES+3)/4, 256, 0, stream>>>(off, csr, ytab, rtab, cw+OFF_B1, h, 0);

    k_pred2<<<BATCH/64, 256, 0, stream>>>(h, srcn, tgtn, cw, bpp1, bpp2, bnf, d_out, flags);
}

// Round 13
// 335.562 us; speedup vs baseline: 1.0848x; 1.0848x over previous
//
#include <hip/hip_runtime.h>
#include <hip/hip_bf16.h>

#define N_NODES 50000
#define N_EDGES 1600000
#define BATCH   16384
#define HID     128
#define NBUCK   782          // (N_NODES+63)/64
#define NBLK    256
#define EPB     6250         // NBLK*EPB == N_EDGES

#define CONVB   967          // ceil(CW_TOT/256)
#define PACKB   577          // ceil(PACK_TOT/256)
#define G0A     782          // gemm0 blocks in mix3a (rows 0..25023)
#define G0B     781          // gemm0 blocks in mix3b (rows 25024..49999)

using short8  = __attribute__((ext_vector_type(8))) short;
using floatx4 = __attribute__((ext_vector_type(4))) float;
using floatv4 = __attribute__((ext_vector_type(4))) float;
using float2v = __attribute__((ext_vector_type(2))) float;
using uint2v  = __attribute__((ext_vector_type(2))) unsigned;
using uintx4  = __attribute__((ext_vector_type(4))) unsigned;
typedef unsigned short ushort_t;

__device__ __forceinline__ float bflo(unsigned u){ return __uint_as_float(u << 16); }
__device__ __forceinline__ float bfhi(unsigned u){ return __uint_as_float(u & 0xffff0000u); }
__device__ __forceinline__ float bf1(ushort_t u){ return __uint_as_float(((unsigned)u) << 16); }
__device__ __forceinline__ ushort_t f2bf(float f){
    unsigned u = __float_as_uint(f);
    return (ushort_t)((u + 0x7fffu + ((u >> 16) & 1u)) >> 16);   // RNE
}
__device__ __forceinline__ int geti(const void* p, long long i, int is64){
    return is64 ? (int)((const long long*)p)[i] : ((const int*)p)[i];
}
__device__ __forceinline__ float2v up2(unsigned u){
    float2v r; r.x = bflo(u); r.y = bfhi(u); return r;
}

// canonical arena offsets (ushort units)
#define OFF_WL0 0
#define OFF_WR0 32768
#define OFF_WL1 65536
#define OFF_WR1 81920
#define OFF_B0  98304
#define OFF_B1  98432
#define OFF_EPW 98560
#define OFF_EPB 98944
#define OFF_P1W 99008
#define OFF_P1B 139968
#define OFF_BNG 140096
#define OFF_BNB 140224
#define OFF_BNM 140352
#define OFF_BNV 140480
#define OFF_P2W 140608
#define OFF_P2B 148800
#define OFF_P3W 148864
#define OFF_EF  148928
#define OFF_P3B 247232
#define CW_TOT  247233
#define PACK_TOT 147584

// ---------------- dtype detection (parallel) ----------------
__global__ void k_detect(const unsigned* __restrict__ xbits,
                         const unsigned* __restrict__ eibits, int* flags){
    __shared__ int f[2];
    int t = threadIdx.x;
    if (t < 2) f[t] = 0;
    __syncthreads();
    unsigned u = xbits[t];
    unsigned e0 = (u >> 7)  & 0xFF;
    unsigned e1 = (u >> 23) & 0xFF;
    if (e0 >= 140 || e1 >= 140) atomicOr(&f[0], 1);
    if (eibits[2*t + 1] != 0)   atomicOr(&f[1], 1);
    __syncthreads();
    if (t == 0){ flags[0] = f[0]; flags[1] = f[1] ? 0 : 1; }
}

#define NT 19
struct ConvDesc { const void* src[NT]; int cum[NT + 1]; };

// ---------------- mix1: weight-arena convert || edge histogram ----------------
__global__ __launch_bounds__(256)
void k_mix1(ConvDesc d, ushort_t* __restrict__ cw,
            const void* __restrict__ ei, int* __restrict__ hist,
            const int* __restrict__ flags){
    __shared__ int lh[NBUCK];
    if (blockIdx.x < CONVB){
        int i = blockIdx.x*256 + threadIdx.x;
        if (i >= d.cum[NT]) return;
        int seg = 0;
        while (i >= d.cum[seg + 1]) seg++;
        int off = i - d.cum[seg];
        ushort_t v;
        if (flags[0]) v = f2bf(((const float*)d.src[seg])[off]);
        else          v = ((const ushort_t*)d.src[seg])[off];
        cw[i] = v;
    } else {
        int b = blockIdx.x - CONVB;
        for (int i = threadIdx.x; i < NBUCK; i += 256) lh[i] = 0;
        __syncthreads();
        int i64 = flags[1];
        int e0 = b * EPB;
        for (int e = e0 + threadIdx.x; e < e0 + EPB; e += 256){
            int dd = geti(ei, (long long)N_EDGES + e, i64);
            atomicAdd(&lh[dd >> 6], 1);
        }
        __syncthreads();
        for (int i = threadIdx.x; i < NBUCK; i += 256)
            hist[i * NBLK + b] = lh[i];
    }
}

// ---------------- mix2: MFMA weight pre-pack + BN fold || scancol ----------------
__global__ __launch_bounds__(256)
void k_mix2(const ushort_t* __restrict__ cw,
            ushort_t* __restrict__ bp0, ushort_t* __restrict__ bp1,
            ushort_t* __restrict__ bpp1, ushort_t* __restrict__ bpp2,
            float* __restrict__ bnf,
            int* __restrict__ hist, int* __restrict__ btot){
    __shared__ int sh[256];
    if (blockIdx.x < PACKB){
        int i = blockIdx.x*256 + threadIdx.x;
        if (i < 65536){
            int j = i & 7, lane = (i >> 3) & 63, c = (i >> 9) & 15, kk = i >> 13;
            int k = kk*32 + (lane >> 4)*8 + j;
            int n = c*16 + (lane & 15);
            bp0[i] = (n < 128) ? cw[OFF_WL0 + k*128 + n] : cw[OFF_WR0 + k*128 + (n-128)];
        } else if (i < 98304){
            int i2 = i - 65536;
            int j = i2 & 7, lane = (i2 >> 3) & 63, c = (i2 >> 9) & 15, kk = i2 >> 13;
            int k = kk*32 + (lane >> 4)*8 + j;
            int n = c*16 + (lane & 15);
            bp1[i2] = (n < 128) ? cw[OFF_WL1 + k*128 + n] : cw[OFF_WR1 + k*128 + (n-128)];
        } else if (i < 139264){
            int i2 = i - 98304;                     // p1_w [320][128] -> frag order
            int j = i2 & 7, lane = (i2 >> 3) & 63, ct = (i2 >> 9) & 7, kk = i2 >> 12;
            int k = kk*32 + (lane >> 4)*8 + j;
            int n = ct*16 + (lane & 15);
            bpp1[i2] = cw[OFF_P1W + k*128 + n];
        } else if (i < 147456){
            int i2 = i - 139264;                    // p2_w [128][64] -> frag order
            int j = i2 & 7, lane = (i2 >> 3) & 63, ct = (i2 >> 9) & 3, kk = i2 >> 11;
            int k = kk*32 + (lane >> 4)*8 + j;
            int n = ct*16 + (lane & 15);
            bpp2[i2] = cw[OFF_P2W + k*64 + n];
        } else if (i < PACK_TOT){
            int n = i - 147456;                     // BN fold: scale/shift fp32
            float g = bf1(cw[OFF_BNG + n]), b = bf1(cw[OFF_BNB + n]);
            float m = bf1(cw[OFF_BNM + n]), v = bf1(cw[OFF_BNV + n]);
            float sc = g / sqrtf(v + 1e-5f);
            bnf[n] = sc; bnf[128 + n] = b - m*sc;
        }
    } else {
        int b = blockIdx.x - PACKB, t = threadIdx.x;
        int v = hist[b*NBLK + t];
        sh[t] = v; __syncthreads();
        for (int o = 1; o < 256; o <<= 1){
            int x = (t >= o) ? sh[t-o] : 0;
            __syncthreads();
            sh[t] += x;
            __syncthreads();
        }
        hist[b*NBLK + t] = sh[t] - v;
        if (t == 255) btot[b] = sh[255];
    }
}

__global__ __launch_bounds__(1024)
void kb_scanbase(const int* __restrict__ btot, int* __restrict__ bbase,
                 int* __restrict__ off){
    __shared__ int sh[1024];
    int t = threadIdx.x;
    int v = (t < NBUCK) ? btot[t] : 0;
    sh[t] = v; __syncthreads();
    for (int o = 1; o < 1024; o <<= 1){
        int x = (t >= o) ? sh[t-o] : 0;
        __syncthreads();
        sh[t] += x;
        __syncthreads();
    }
    if (t < NBUCK) bbase[t] = sh[t] - v;
    if (t == 0){ bbase[NBUCK] = N_EDGES; off[N_NODES] = N_EDGES; }
}

// ---------------- unified layer-0 GEMM body (bf16 or fp32 A at runtime) ----------------
// 32-row block, wave = 16 rows x 128 cols. Col-half 0 -> ytab, col-half 1 -> rtab
// (split tables halve the k_agg gather working set: 25.6 -> 12.8 MB).
__device__ __forceinline__ void gemm0_body(const void* __restrict__ xin,
                                           const ushort_t* __restrict__ Bp,
                                           ushort_t* __restrict__ ytab,
                                           ushort_t* __restrict__ rtab,
                                           int M, int f32, int blk){
    const int t = threadIdx.x;
    const int lane = t & 63;
    const int w = t >> 6;
    const int rg = w >> 1, cg = w & 1;
    const int l16 = lane & 15, q = lane >> 4;
    const int m_base = blk * 32 + rg * 16;
    int m = m_base + l16;
    bool ok = (m < M);
    const short8* bbase = (const short8*)Bp + lane;

    floatx4 acc[8] = {};
    if (f32){
        const float* arow = (const float*)xin + (size_t)(ok ? m : 0)*256 + q*8;
        for (int kk = 0; kk < 8; ++kk){
            union { unsigned u[4]; short8 s; } cv;
            cv.u[0]=0; cv.u[1]=0; cv.u[2]=0; cv.u[3]=0;
            if (ok){
                floatv4 f0 = *(const floatv4*)(arow + kk*32);
                floatv4 f1 = *(const floatv4*)(arow + kk*32 + 4);
                cv.u[0] = __builtin_amdgcn_perm(__float_as_uint(f0.y), __float_as_uint(f0.x), 0x07060302);
                cv.u[1] = __builtin_amdgcn_perm(__float_as_uint(f0.w), __float_as_uint(f0.z), 0x07060302);
                cv.u[2] = __builtin_amdgcn_perm(__float_as_uint(f1.y), __float_as_uint(f1.x), 0x07060302);
                cv.u[3] = __builtin_amdgcn_perm(__float_as_uint(f1.w), __float_as_uint(f1.z), 0x07060302);
            }
            #pragma unroll
            for (int ci = 0; ci < 8; ++ci){
                short8 b = bbase[(kk*16 + cg*8 + ci)*64];
                acc[ci] = __builtin_amdgcn_mfma_f32_16x16x32_bf16(cv.s, b, acc[ci], 0, 0, 0);
            }
        }
    } else {
        const ushort_t* arow = (const ushort_t*)xin + (size_t)(ok ? m : 0)*256 + q*8;
        for (int kk = 0; kk < 8; ++kk){
            short8 a = {0,0,0,0,0,0,0,0};
            if (ok) a = *(const short8*)(arow + kk*32);
            #pragma unroll
            for (int ci = 0; ci < 8; ++ci){
                short8 b = bbase[(kk*16 + cg*8 + ci)*64];
                acc[ci] = __builtin_amdgcn_mfma_f32_16x16x32_bf16(a, b, acc[ci], 0, 0, 0);
            }
        }
    }
    ushort_t* dst = cg ? rtab : ytab;
    int row_b = m_base + q*4;
    #pragma unroll
    for (int r = 0; r < 4; ++r){
        int row = row_b + r;
        if (row < M){
            #pragma unroll
            for (int ci = 0; ci < 8; ++ci)
                dst[(size_t)row*128 + ci*16 + l16] = f2bf(acc[ci][r]);
        }
    }
}

// ---------------- mix3a: gemm0 rows 0..25023 (blocks < G0A) || edge scatter ----------------
__global__ __launch_bounds__(256)
void k_mix3a(const void* __restrict__ x, const ushort_t* __restrict__ bp0,
             ushort_t* __restrict__ ytab, ushort_t* __restrict__ rtab,
             const void* __restrict__ ei, const int* __restrict__ hist,
             const int* __restrict__ bbase, unsigned* __restrict__ ebuf,
             const int* __restrict__ flags){
    __shared__ int lcur[NBUCK];
    if (blockIdx.x < G0A){
        gemm0_body(x, bp0, ytab, rtab, N_NODES, flags[0], blockIdx.x);
    } else {
        int b = blockIdx.x - G0A;
        for (int i = threadIdx.x; i < NBUCK; i += 256)
            lcur[i] = bbase[i] + hist[i*NBLK + b];
        __syncthreads();
        int i64 = flags[1];
        int e0 = b * EPB;
        for (int e = e0 + threadIdx.x; e < e0 + EPB; e += 256){
            int s = geti(ei, e, i64);
            int d = geti(ei, (long long)N_EDGES + e, i64);
            int p = atomicAdd(&lcur[d >> 6], 1);
            ebuf[p] = (unsigned)s | ((unsigned)(d & 63) << 16);
        }
    }
}

// ---------------- mix3b: gemm0 rows 25024..49999 (blocks < G0B) || per-bucket CSR ----------------
__global__ __launch_bounds__(256)
void k_mix3b(const void* __restrict__ x, const ushort_t* __restrict__ bp0,
             ushort_t* __restrict__ ytab, ushort_t* __restrict__ rtab,
             const unsigned* __restrict__ ebuf, const int* __restrict__ bbase,
             ushort_t* __restrict__ csr, int* __restrict__ off,
             const int* __restrict__ flags){
    __shared__ int ldeg[64];
    if (blockIdx.x < G0B){
        gemm0_body(x, bp0, ytab, rtab, N_NODES, flags[0], G0A + blockIdx.x);
    } else {
        int b = blockIdx.x - G0B, t = threadIdx.x;
        int ebase = bbase[b], eend = bbase[b+1];
        if (t < 64) ldeg[t] = 0;
        __syncthreads();
        for (int i = ebase + t; i < eend; i += 256)
            atomicAdd(&ldeg[(ebuf[i] >> 16) & 63], 1);
        __syncthreads();
        if (t < 64){
            int v = ldeg[t];
            int sum = v;
            #pragma unroll
            for (int o = 1; o < 64; o <<= 1){
                int x2 = __shfl_up(sum, o, 64);
                if (t >= o) sum += x2;
            }
            int excl = sum - v;
            int node = b*64 + t;
            if (node < N_NODES) off[node] = ebase + excl;
            ldeg[t] = excl;
        }
        __syncthreads();
        for (int i = ebase + t; i < eend; i += 256){
            unsigned u = ebuf[i];
            int p = atomicAdd(&ldeg[(u >> 16) & 63], 1);
            csr[ebase + p] = (ushort_t)(u & 0xffffu);
        }
    }
}

// ---------------- layer-1 GEMM (bf16 A): 32-row block, split outputs ----------------
__global__ __launch_bounds__(256)
void k_gemm1(const ushort_t* __restrict__ A, const ushort_t* __restrict__ Bp,
             ushort_t* __restrict__ ytab, ushort_t* __restrict__ rtab, int M)
{
    const int KSTEPS = 4;
    const int lane = threadIdx.x & 63;
    const int w    = threadIdx.x >> 6;
    const int rg   = w >> 1;
    const int cg   = w & 1;
    const int l16  = lane & 15;
    const int q    = lane >> 4;
    const int S    = KSTEPS * 32;
    const int m_base = blockIdx.x * 32 + rg * 16;

    int m = m_base + l16;
    bool ok = (m < M);
    const ushort_t* arow = A + (size_t)(ok ? m : 0) * S + q*8;
    const short8* bbase = (const short8*)Bp + lane;

    floatx4 acc[8] = {};
    for (int kk = 0; kk < KSTEPS; ++kk){
        short8 a = {0,0,0,0,0,0,0,0};
        if (ok) a = *(const short8*)(arow + kk*32);
        #pragma unroll
        for (int ci = 0; ci < 8; ++ci){
            short8 b = bbase[(kk*16 + cg*8 + ci)*64];
            acc[ci] = __builtin_amdgcn_mfma_f32_16x16x32_bf16(a, b, acc[ci], 0, 0, 0);
        }
    }

    ushort_t* dst = cg ? rtab : ytab;
    int row_b = m_base + q*4;
    #pragma unroll
    for (int r = 0; r < 4; ++r){
        int row = row_b + r;
        if (row < M){
            #pragma unroll
            for (int ci = 0; ci < 8; ++ci)
                dst[(size_t)row*128 + ci*16 + l16] = f2bf(acc[ci][r]);
        }
    }
}

// ---------------- Aggregation: out[v] = mean(ytab[csr]) + bias + rtab[v] ----------------
// Wave per node; 16-lane groups g cover edges p+g; lane covers 16B of the 256B row.
// FOUR independent streams (16 edges, 4KB in flight). Gather table = 12.8 MB.
__global__ __launch_bounds__(256)
void k_agg(const int* __restrict__ off, const ushort_t* __restrict__ csr,
           const ushort_t* __restrict__ ytab, const ushort_t* __restrict__ rtab,
           const ushort_t* __restrict__ bias,
           ushort_t* __restrict__ out, int do_relu)
{
    int v = blockIdx.x*4 + (threadIdx.x >> 6);
    if (v >= N_NODES) return;
    const int l = threadIdx.x & 63;
    const int g = l >> 4;          // edge subgroup
    const int c = l & 15;          // 16B chunk: bf16 cols c*8..c*8+8
    int e0 = off[v], e1 = off[v+1];
    const ushort_t* yb = ytab + c*8;

    float2v A0[4] = {}, A1[4] = {}, A2[4] = {}, A3[4] = {};
    int p = e0;
    for (; p + 16 <= e1; p += 16){
        int u0 = csr[p + g];
        int u1 = csr[p + 4 + g];
        int u2 = csr[p + 8 + g];
        int u3 = csr[p + 12 + g];
        uintx4 d0 = *(const uintx4*)(yb + (size_t)u0*128);
        uintx4 d1 = *(const uintx4*)(yb + (size_t)u1*128);
        uintx4 d2 = *(const uintx4*)(yb + (size_t)u2*128);
        uintx4 d3 = *(const uintx4*)(yb + (size_t)u3*128);
        A0[0] += up2(d0.x); A0[1] += up2(d0.y); A0[2] += up2(d0.z); A0[3] += up2(d0.w);
        A1[0] += up2(d1.x); A1[1] += up2(d1.y); A1[2] += up2(d1.z); A1[3] += up2(d1.w);
        A2[0] += up2(d2.x); A2[1] += up2(d2.y); A2[2] += up2(d2.z); A2[3] += up2(d2.w);
        A3[0] += up2(d3.x); A3[1] += up2(d3.y); A3[2] += up2(d3.z); A3[3] += up2(d3.w);
    }
    for (; p + 4 <= e1; p += 4){
        int u0 = csr[p + g];
        uintx4 d0 = *(const uintx4*)(yb + (size_t)u0*128);
        A0[0] += up2(d0.x); A0[1] += up2(d0.y); A0[2] += up2(d0.z); A0[3] += up2(d0.w);
    }
    if (p + g < e1){
        int u1 = csr[p + g];
        uintx4 d1 = *(const uintx4*)(yb + (size_t)u1*128);
        A1[0] += up2(d1.x); A1[1] += up2(d1.y); A1[2] += up2(d1.z); A1[3] += up2(d1.w);
    }
    #pragma unroll
    for (int j = 0; j < 4; ++j) A0[j] += A1[j] + A2[j] + A3[j];

    float a0=A0[0].x, a1=A0[0].y, a2=A0[1].x, a3=A0[1].y;
    float a4=A0[2].x, a5=A0[2].y, a6=A0[3].x, a7=A0[3].y;
    #pragma unroll
    for (int m = 16; m <= 32; m <<= 1){
        a0 += __shfl_xor(a0, m, 64); a1 += __shfl_xor(a1, m, 64);
        a2 += __shfl_xor(a2, m, 64); a3 += __shfl_xor(a3, m, 64);
        a4 += __shfl_xor(a4, m, 64); a5 += __shfl_xor(a5, m, 64);
        a6 += __shfl_xor(a6, m, 64); a7 += __shfl_xor(a7, m, 64);
    }
    if (g == 0){
        float inv = 1.f / (float)max(e1 - e0, 1);
        uintx4 rr = *(const uintx4*)(rtab + (size_t)v*128 + c*8);
        uintx4 bb = *(const uintx4*)(bias + c*8);
        float v0 = a0*inv + bflo(rr.x) + bflo(bb.x);
        float v1 = a1*inv + bfhi(rr.x) + bfhi(bb.x);
        float v2 = a2*inv + bflo(rr.y) + bflo(bb.y);
        float v3 = a3*inv + bfhi(rr.y) + bfhi(bb.y);
        float v4 = a4*inv + bflo(rr.z) + bflo(bb.z);
        float v5 = a5*inv + bfhi(rr.z) + bfhi(bb.z);
        float v6 = a6*inv + bflo(rr.w) + bflo(bb.w);
        float v7 = a7*inv + bfhi(rr.w) + bfhi(bb.w);
        if (do_relu){
            v0=fmaxf(v0,0.f); v1=fmaxf(v1,0.f); v2=fmaxf(v2,0.f); v3=fmaxf(v3,0.f);
            v4=fmaxf(v4,0.f); v5=fmaxf(v5,0.f); v6=fmaxf(v6,0.f); v7=fmaxf(v7,0.f);
        }
        uintx4 o;
        o.x = (unsigned)f2bf(v0) | ((unsigned)f2bf(v1) << 16);
        o.y = (unsigned)f2bf(v2) | ((unsigned)f2bf(v3) << 16);
        o.z = (unsigned)f2bf(v4) | ((unsigned)f2bf(v5) << 16);
        o.w = (unsigned)f2bf(v6) | ((unsigned)f2bf(v7) << 16);
        *(uintx4*)(out + (size_t)v*128 + c*8) = o;
    }
}

// ---------------- MFMA predictor: one block = 64 batch rows ----------------
__global__ __launch_bounds__(256)
void k_pred2(const ushort_t* __restrict__ h2,
             const void* __restrict__ srcn, const void* __restrict__ tgtn,
             const ushort_t* __restrict__ cw, const ushort_t* __restrict__ bpp1,
             const ushort_t* __restrict__ bpp2, const float* __restrict__ bnf,
             void* __restrict__ outp, const int* __restrict__ flags)
{
    __shared__ ushort_t comb[64][328];
    __shared__ ushort_t zbuf[64][136];
    __shared__ ushort_t z2buf[64][68];
    __shared__ float    partial[4][64];
    __shared__ int      sid[64], tid_[64];

    const int t    = threadIdx.x;
    const int lane = t & 63;
    const int w    = t >> 6;
    const int l16  = lane & 15;
    const int q    = lane >> 4;
    const int row0 = blockIdx.x * 64;
    const int i64  = flags[1];

    if (t < 64){ sid[t] = geti(srcn, row0 + t, i64); tid_[t] = geti(tgtn, row0 + t, i64); }
    __syncthreads();

    const unsigned* h2u = (const unsigned*)h2;
    #pragma unroll 4
    for (int r = w*16; r < w*16 + 16; ++r){
        unsigned us = h2u[(size_t)sid[r]*64 + lane];
        unsigned ut = h2u[(size_t)tid_[r]*64 + lane];
        *(unsigned*)&comb[r][2*lane]       = us;
        *(unsigned*)&comb[r][128 + 2*lane] = ut;
    }
    {
        int r = t >> 2, c0 = (t & 3) * 16;
        float efv[6];
        #pragma unroll
        for (int k = 0; k < 6; ++k) efv[k] = bf1(cw[OFF_EF + (row0 + r)*6 + k]);
        #pragma unroll
        for (int c = 0; c < 16; ++c){
            int n = c0 + c;
            float a = bf1(cw[OFF_EPB + n]);
            #pragma unroll
            for (int k = 0; k < 6; ++k) a += efv[k] * bf1(cw[OFF_EPW + k*64 + n]);
            comb[r][256 + n] = f2bf(fmaxf(a, 0.f));
        }
    }
    __syncthreads();

    floatx4 acc[4][2] = {};
    for (int kk = 0; kk < 10; ++kk){
        short8 a[4];
        #pragma unroll
        for (int rt = 0; rt < 4; ++rt)
            a[rt] = *(const short8*)&comb[rt*16 + l16][kk*32 + q*8];
        #pragma unroll
        for (int ci = 0; ci < 2; ++ci){
            short8 b = *(const short8*)&bpp1[(((kk*8) + (w*2 + ci))*64 + lane)*8];
            #pragma unroll
            for (int rt = 0; rt < 4; ++rt)
                acc[rt][ci] = __builtin_amdgcn_mfma_f32_16x16x32_bf16(a[rt], b, acc[rt][ci], 0, 0, 0);
        }
    }
    #pragma unroll
    for (int ci = 0; ci < 2; ++ci){
        int n = w*32 + ci*16 + l16;
        float b1v = bf1(cw[OFF_P1B + n]);
        float sc = bnf[n], sh = bnf[128 + n];
        #pragma unroll
        for (int rt = 0; rt < 4; ++rt)
            #pragma unroll
            for (int r = 0; r < 4; ++r){
                float v = fmaxf(acc[rt][ci][r] + b1v, 0.f) * sc + sh;
                zbuf[rt*16 + q*4 + r][n] = f2bf(v);
            }
    }
    __syncthreads();

    floatx4 acc2[4] = {};
    for (int kk = 0; kk < 4; ++kk){
        short8 b = *(const short8*)&bpp2[(((kk*4) + w)*64 + lane)*8];
        #pragma unroll
        for (int rt = 0; rt < 4; ++rt){
            short8 a = *(const short8*)&zbuf[rt*16 + l16][kk*32 + q*8];
            acc2[rt] = __builtin_amdgcn_mfma_f32_16x16x32_bf16(a, b, acc2[rt], 0, 0, 0);
        }
    }
    {
        int n = w*16 + l16;
        float b2v = bf1(cw[OFF_P2B + n]);
        #pragma unroll
        for (int rt = 0; rt < 4; ++rt)
            #pragma unroll
            for (int r = 0; r < 4; ++r)
                z2buf[rt*16 + q*4 + r][n] = f2bf(fmaxf(acc2[rt][r] + b2v, 0.f));
    }
    __syncthreads();

    {
        int r = t & 63, seg = t >> 6;
        float s = 0.f;
        #pragma unroll
        for (int c = 0; c < 16; ++c){
            int n = seg*16 + c;
            s += bf1(z2buf[r][n]) * bf1(cw[OFF_P3W + n]);
        }
        partial[seg][r] = s;
    }
    __syncthreads();
    if (t < 64){
        float zf = partial[0][t] + partial[1][t] + partial[2][t] + partial[3][t] + bf1(cw[OFF_P3B]);
        float sg = 1.f / (1.f + __expf(-zf));
        if (flags[0]) ((float*)outp)[row0 + t] = sg;
        else          ((ushort_t*)outp)[row0 + t] = f2bf(sg);
    }
}

extern "C" void kernel_launch(void* const* d_in, const int* in_sizes, int n_in,
                              void* d_out, int out_size, void* d_ws, size_t ws_size,
                              hipStream_t stream)
{
    const void* x    = d_in[0];
    const void* ei   = d_in[1];
    const void* srcn = d_in[2];
    const void* tgtn = d_in[3];

    char* p = (char*)d_ws;
    auto carve = [&](size_t bytes)->char*{ char* r = p; p += (bytes + 511) & ~size_t(511); return r; };
    int* flags = (int*)carve(64);
    int* off   = (int*)carve((N_NODES+1)*4);
    int* btot  = (int*)carve(NBUCK*4);
    int* bbase = (int*)carve((NBUCK+1)*4);
    ushort_t* csr  = (ushort_t*)carve((size_t)N_EDGES*2);
    ushort_t* ytab = (ushort_t*)carve((size_t)N_NODES*128*2);
    ushort_t* rtab = (ushort_t*)carve((size_t)N_NODES*128*2);
    ushort_t* h    = (ushort_t*)carve((size_t)N_NODES*128*2);
    ushort_t* cw   = (ushort_t*)carve((size_t)CW_TOT*2);
    ushort_t* bp0  = (ushort_t*)carve((size_t)65536*2);
    ushort_t* bp1  = (ushort_t*)carve((size_t)32768*2);
    ushort_t* bpp1 = (ushort_t*)carve((size_t)40960*2);
    ushort_t* bpp2 = (ushort_t*)carve((size_t)8192*2);
    float*    bnf  = (float*)carve(256*4);

    // hist (0.8 MB) + ebuf (6.4 MB) alias into h (12.8 MB): h is first written
    // by k_agg(relu=1), which runs AFTER kb_csr (inside mix3b) consumed ebuf.
    int*      hist = (int*)h;
    unsigned* ebuf = (unsigned*)((char*)h + 1u*1024*1024);

    k_detect<<<1, 256, 0, stream>>>((const unsigned*)x, (const unsigned*)ei, flags);

    ConvDesc cd;
    const int srcidx[NT] = {5,7,8,10,6,9,11,12,13,14,15,16,17,18,19,20,21,4,22};
    const int lens[NT]   = {32768,32768,16384,16384,128,128,384,64,40960,128,128,128,128,128,8192,64,64,98304,1};
    int run = 0;
    for (int i = 0; i < NT; ++i){ cd.src[i] = d_in[srcidx[i]]; cd.cum[i] = run; run += lens[i]; }
    cd.cum[NT] = run;

    k_mix1<<<CONVB + NBLK, 256, 0, stream>>>(cd, cw, ei, hist, flags);
    k_mix2<<<PACKB + NBUCK, 256, 0, stream>>>(cw, bp0, bp1, bpp1, bpp2, bnf, hist, btot);
    kb_scanbase<<<1, 1024, 0, stream>>>(btot, bbase, off);
    k_mix3a<<<G0A + NBLK, 256, 0, stream>>>(x, bp0, ytab, rtab, ei, hist, bbase, ebuf, flags);
    k_mix3b<<<G0B + NBUCK, 256, 0, stream>>>(x, bp0, ytab, rtab, ebuf, bbase, csr, off, flags);

    k_agg<<<(N_NODES+3)/4, 256, 0, stream>>>(off, csr, ytab, rtab, cw+OFF_B0, h, 1);
    k_gemm1<<<(N_NODES + 31)/32, 256, 0, stream>>>(h, bp1, ytab, rtab, N_NODES);
    k_agg<<<(N_NODES+3)/4, 256, 0, stream>>>(off, csr, ytab, rtab, cw+OFF_B1, h, 0);

    k_pred2<<<BATCH/64, 256, 0, stream>>>(h, srcn, tgtn, cw, bpp1, bpp2, bnf, d_out, flags);
}